// Round 8
// baseline (380.890 us; speedup 1.0000x reference)
//
#include <hip/hip_runtime.h>

// Problem constants (reference: T=128, L=32, C=4, B=32, D=512)
#define TT 128
#define LL 32
#define CC 4
#define BB 32
#define DD 512
#define D4 (DD / 4)   // 128 float4 per D-row

// Native clang vector type: legal operand for __builtin_nontemporal_store
typedef float fx4 __attribute__((ext_vector_type(4)));

__device__ __forceinline__ void nt_store(fx4 v, const fx4* p) {
    __builtin_nontemporal_store(v, (fx4*)p);
}

// ---------------------------------------------------------------------------
// Kernel 1: inclusive prefix sum of f over t, per (b, d4-lane), float4-wide.
// P layout: [B][T+1][D], P[b][0][:]=0, P[b][t+1][:]=sum_{u<=t} f[b][u][:].
// ---------------------------------------------------------------------------
__global__ __launch_bounds__(64) void prefix_kernel(const fx4* __restrict__ f4,
                                                    fx4* __restrict__ P4) {
    int idx = blockIdx.x * 64 + threadIdx.x;   // B*D4 = 4096
    int b = idx >> 7;                           // D4 = 128
    int d4 = idx & (D4 - 1);
    const fx4* fp = f4 + (size_t)b * TT * D4 + d4;
    fx4* Pp = P4 + (size_t)b * (TT + 1) * D4 + d4;
    fx4 acc = (fx4)0.f;
    Pp[0] = acc;
#pragma unroll 16
    for (int t = 0; t < TT; ++t) {
        acc += fp[(size_t)t * D4];
        Pp[(size_t)(t + 1) * D4] = acc;
    }
}

// ---------------------------------------------------------------------------
// Kernel 2: fill-shaped grid-stride kernel over the FLAT output space.
// fc [0, FC4) then fm [FC4, FC4+FM4) then fb — three tight loops, each with
// pow2 decode (shifts/masks only). Window (i,j): ws=j-i+1, clip c covers
// frames [4i+c*ws, 4i+(c+1)*ws):
//   fc[b,i,j,c,:] = (P[4i+(c+1)ws] - P[4i+c*ws]) * mask/ws
//   fm[b,i,j,:]   = (P[4i+4ws] - P[4i]) * mask/(4ws)
//   fb[b,l,:]     = (P[4l+4] - P[4l]) / 4
// j<i -> exact zeros (Wc rows identically zero; d_out is poisoned).
// Emergent locality: at grid-stride iteration k of the fc loop, all 524288
// threads cover exactly batch b=k's 8 MB fc slice -> only P_b (264 KB) is
// live, L2-hot on every XCD. Stores are nontemporal (write-once stream).
// 2048 blocks x 256 threads = 8192 waves = full 32-wave/CU occupancy;
// 32 fc + 8 fm iterations per thread give the compiler a deep pipeline.
// ---------------------------------------------------------------------------
__global__ __launch_bounds__(256) void fused_flat(const fx4* __restrict__ P4,
                                                  const float* __restrict__ mask,
                                                  fx4* __restrict__ out) {
    const size_t FC4 = (size_t)BB * LL * LL * CC * D4;   // 16,777,216
    const size_t FM4 = (size_t)BB * LL * LL * D4;        //  4,194,304
    const size_t FB4 = (size_t)BB * LL * D4;             //    131,072
    const size_t stride = (size_t)gridDim.x * 256;
    const size_t t0 = (size_t)blockIdx.x * 256 + threadIdx.x;

    fx4* fc = out;
    fx4* fm = out + FC4;
    fx4* fb = out + FC4 + FM4;

    for (size_t idx = t0; idx < FC4; idx += stride) {
        int d4 = (int)idx & (D4 - 1);
        int row = (int)(idx >> 7);         // blk*CC + c
        int c = row & (CC - 1);
        int blk = row >> 2;
        int j = blk & (LL - 1);
        int i = (blk >> 5) & (LL - 1);
        int b = blk >> 10;
        fx4 v = (fx4)0.f;
        if (j >= i) {
            int ws = j - i + 1;
            const fx4* Pl = P4 + (size_t)(b * (TT + 1) + 4 * i + c * ws) * D4 + d4;
            fx4 lo = Pl[0];
            fx4 hi = Pl[(size_t)ws * D4];
            float sc = mask[blk] * __builtin_amdgcn_rcpf((float)ws);
            v = (hi - lo) * sc;
        }
        nt_store(v, fc + idx);
    }

    for (size_t idx = t0; idx < FM4; idx += stride) {
        int d4 = (int)idx & (D4 - 1);
        int blk = (int)(idx >> 7);
        int j = blk & (LL - 1);
        int i = (blk >> 5) & (LL - 1);
        int b = blk >> 10;
        fx4 v = (fx4)0.f;
        if (j >= i) {
            int ws = j - i + 1;
            const fx4* Pb = P4 + (size_t)(b * (TT + 1)) * D4 + d4;
            fx4 lo = Pb[(size_t)(4 * i) * D4];
            fx4 hi = Pb[(size_t)(4 * i + 4 * ws) * D4];
            float sc = 0.25f * mask[blk] * __builtin_amdgcn_rcpf((float)ws);
            v = (hi - lo) * sc;
        }
        nt_store(v, fm + idx);
    }

    for (size_t idx = t0; idx < FB4; idx += stride) {
        int d4 = (int)idx & (D4 - 1);
        int bl = (int)(idx >> 7);          // b*LL + l
        int l = bl & (LL - 1);
        int b = bl >> 5;
        const fx4* Pb = P4 + (size_t)(b * (TT + 1)) * D4 + d4;
        fx4 lo = Pb[(size_t)(4 * l) * D4];
        fx4 hi = Pb[(size_t)(4 * l + 4) * D4];
        nt_store((hi - lo) * 0.25f, fb + idx);
    }
}

// ---------------------------------------------------------------------------
// Fallback path (workspace too small): direct window sums from f.
// ---------------------------------------------------------------------------
__global__ __launch_bounds__(256) void fcfm_direct(const float* __restrict__ f,
                                                   const float* __restrict__ mask,
                                                   float* __restrict__ fc,
                                                   float* __restrict__ fm) {
    int blk = blockIdx.x;
    int j = blk & (LL - 1);
    int i = (blk >> 5) & (LL - 1);
    int b = blk >> 10;
    int tid = threadIdx.x;
    float* fc_out = fc + (size_t)blk * CC * DD;
    float* fm_out = fm + (size_t)blk * DD;

    if (j < i) {
        fx4 z = (fx4)0.f;
        fx4* fcv = (fx4*)fc_out;
#pragma unroll
        for (int k = 0; k < 2; ++k) fcv[tid + k * 256] = z;
        fx4* fmv = (fx4*)fm_out;
        if (tid < DD / 4) fmv[tid] = z;
        return;
    }

    int ws = j - i + 1;
    float sc = mask[blk] / (float)ws;
    const float* fbase = f + (size_t)b * TT * DD;

#pragma unroll
    for (int r = 0; r < 2; ++r) {
        int dd = tid + r * 256;
        float tot = 0.f;
#pragma unroll
        for (int c = 0; c < CC; ++c) {
            float s = 0.f;
            int t0 = 4 * i + c * ws;
            for (int t = 0; t < ws; ++t) s += fbase[(size_t)(t0 + t) * DD + dd];
            fc_out[c * DD + dd] = s * sc;
            tot += s;
        }
        fm_out[dd] = tot * sc * 0.25f;
    }
}

__global__ __launch_bounds__(256) void fb_direct(const float* __restrict__ f,
                                                 float* __restrict__ fb) {
    int idx = blockIdx.x * 256 + threadIdx.x;
    int d = idx & (DD - 1);
    int l = (idx >> 9) & (LL - 1);
    int b = idx >> 14;
    const float* fp = f + (size_t)b * TT * DD + d;
    int t0 = 4 * l;
    fb[idx] = (fp[(size_t)t0 * DD] + fp[(size_t)(t0 + 1) * DD] +
               fp[(size_t)(t0 + 2) * DD] + fp[(size_t)(t0 + 3) * DD]) * 0.25f;
}

extern "C" void kernel_launch(void* const* d_in, const int* in_sizes, int n_in,
                              void* d_out, int out_size, void* d_ws, size_t ws_size,
                              hipStream_t stream) {
    const float* f    = (const float*)d_in[0];   // [B,T,D]
    const float* mask = (const float*)d_in[1];   // [B,L,L]
    // d_in[2] = Wc, folded analytically (unused)

    float* out = (float*)d_out;
    const size_t fc_elems = (size_t)BB * LL * LL * CC * DD;   // 67,108,864
    const size_t fm_elems = (size_t)BB * LL * LL * DD;        // 16,777,216
    float* fc = out;
    float* fm = out + fc_elems;
    float* fb = out + fc_elems + fm_elems;

    const size_t P_bytes = (size_t)BB * (TT + 1) * DD * sizeof(float);  // ~8.45 MB

    if (ws_size >= P_bytes) {
        float* P = (float*)d_ws;
        prefix_kernel<<<(BB * D4) / 64, 64, 0, stream>>>((const fx4*)f,
                                                         (fx4*)P);
        fused_flat<<<2048, 256, 0, stream>>>((const fx4*)P, mask, (fx4*)out);
    } else {
        fcfm_direct<<<BB * LL * LL, 256, 0, stream>>>(f, mask, fc, fm);
        fb_direct<<<(BB * LL * DD) / 256, 256, 0, stream>>>(f, fb);
    }
}